// Round 4
// baseline (272.084 us; speedup 1.0000x reference)
//
#include <hip/hip_runtime.h>
#include <stdint.h>

#define IN1 16
#define HIDC 10
#define OUT3 16
#define NTYPES 25
#define MAXB 32

// ---------------- zero two int regions ----------------
__global__ __launch_bounds__(256) void zero2_kernel(int* __restrict__ a, int na,
                                                    int* __restrict__ b, int nb) {
  int i = blockIdx.x * blockDim.x + threadIdx.x;
  int s = gridDim.x * blockDim.x;
  for (int j = i; j < na; j += s) a[j] = 0;
  for (int j = i; j < nb; j += s) b[j] = 0;
}

// ---------------- histogram + within-bucket rank (1 atomic per edge) ----------
__global__ __launch_bounds__(256) void hist_kernel(const int* __restrict__ edst,
                                                   int* __restrict__ deg,
                                                   int* __restrict__ pos, int E) {
  int e = blockIdx.x * blockDim.x + threadIdx.x;
  if (e < E) pos[e] = atomicAdd(&deg[edst[e]], 1);
}

// ---------------- hierarchical scan: A) per-1024-chunk local scan + chunk sum
__global__ __launch_bounds__(256) void scan_part_kernel(const int* __restrict__ deg,
                                                        int* __restrict__ row_ptr,
                                                        int* __restrict__ bsum, int N) {
  __shared__ int wsums[4];
  int tid = threadIdx.x, lane = tid & 63, wid = tid >> 6;
  int idx0 = (blockIdx.x * 256 + tid) * 4;      // 4 scalar elements per thread
  int4 v = make_int4(0, 0, 0, 0);
  if (idx0 < N)     v.x = deg[idx0];
  if (idx0 + 1 < N) v.y = deg[idx0 + 1];
  if (idx0 + 2 < N) v.z = deg[idx0 + 2];
  if (idx0 + 3 < N) v.w = deg[idx0 + 3];
  int s = v.x + v.y + v.z + v.w;
  int x = s;
  #pragma unroll
  for (int off = 1; off < 64; off <<= 1) {
    int y = __shfl_up(x, off);
    if (lane >= off) x += y;
  }
  if (lane == 63) wsums[wid] = x;
  __syncthreads();
  int wpre = 0;
  #pragma unroll
  for (int w = 0; w < 4; ++w) if (w < wid) wpre += wsums[w];
  int excl = x - s + wpre;                      // block-local exclusive prefix
  if (idx0 < N)     row_ptr[idx0]     = excl;
  if (idx0 + 1 < N) row_ptr[idx0 + 1] = excl + v.x;
  if (idx0 + 2 < N) row_ptr[idx0 + 2] = excl + v.x + v.y;
  if (idx0 + 3 < N) row_ptr[idx0 + 3] = excl + v.x + v.y + v.z;
  if (tid == 255) bsum[blockIdx.x] = excl + s;  // chunk total
}

// B) single-wave exclusive scan of chunk sums (G <= 64); writes row_ptr[N]=E
__global__ __launch_bounds__(64) void scan_bsum_kernel(int* __restrict__ bsum,
                                                       int* __restrict__ row_ptr,
                                                       int G, int N) {
  int tid = threadIdx.x;
  int v = (tid < G) ? bsum[tid] : 0;
  int x = v;
  #pragma unroll
  for (int off = 1; off < 64; off <<= 1) {
    int y = __shfl_up(x, off);
    if (tid >= off) x += y;
  }
  if (tid < G) bsum[tid] = x - v;               // exclusive chunk offsets
  if (tid == 63) row_ptr[N] = x;                // grand total
}

// C) add chunk offset to each local prefix
__global__ __launch_bounds__(256) void scan_add_kernel(int* __restrict__ row_ptr,
                                                       const int* __restrict__ bsum,
                                                       int N) {
  int i = blockIdx.x * blockDim.x + threadIdx.x;
  if (i < N) row_ptr[i] += bsum[i >> 10];
}

// ---------------- scatter edges into CSR order (plain stores) ----------------
__global__ __launch_bounds__(256) void permute_kernel(
    const int* __restrict__ edst, const int* __restrict__ esrc,
    const int* __restrict__ et, const float2* __restrict__ ef,
    const int* __restrict__ row_ptr, const int* __restrict__ pos,
    int4* __restrict__ edges, int E) {
  int e = blockIdx.x * blockDim.x + threadIdx.x;
  if (e >= E) return;
  int d = edst[e];
  int idx = row_ptr[d] + pos[e];
  float2 f = ef[e];
  int4 r;
  r.x = esrc[e];
  r.y = et[e];
  r.z = __float_as_int(f.x);
  r.w = __float_as_int(f.y);
  edges[idx] = r;
}

// ---------------- fused gather layer: msg-agg + mean + root + bias + relu -----
// R0 inner-loop structure (LDS coefs, 16 lanes/node), but PERSISTENT blocks:
// grid sized so all blocks are co-resident -> LDS preamble paid once, not
// once per 16 nodes.  Each WAVE strides independently over 4-node work tiles
// (finer than block-striding: +-1-tile tail ~2 us, no barriers in the loop).
// emb LDS fill vectorized float4 (ESTR % 4 == 0 keeps 16B alignment).
template<int IN_C, int O, bool POOL, int BS>
__global__ __launch_bounds__(BS) void layer_kernel(
    const float* __restrict__ xin,      // [N, IN_C]
    const int4* __restrict__ edges,     // CSR by dst: {src, type, f0, f1}
    const int* __restrict__ row_ptr,    // [N+1]
    const float* __restrict__ emb,      // [25, D]
    const float* __restrict__ wh, const float* __restrict__ bh,
    const float* __restrict__ wg, const float* __restrict__ bg,
    const float* __restrict__ root,     // [IN_C, O]
    const float* __restrict__ bias,     // [O]
    float* __restrict__ hout,           // [N, O], or psum[B*16] if POOL
    const int* __restrict__ ctype, const int* __restrict__ bids,
    float* __restrict__ pcnt,           // [B] (POOL only)
    int N, int B)
{
  constexpr int D = IN_C * O;
  constexpr int ESTR = D + 8;           // multiple of 4 -> float4-aligned rows
  static_assert(ESTR % 4 == 0, "ESTR must keep float4 alignment");
  static_assert((NTYPES * D) % 4 == 0, "emb size must be float4-divisible");
  static_assert(D % 4 == 0, "emb row must be float4-divisible");
  __shared__ float4 s_pa[D];            // {wh0,wh1,wg0,wg1}
  __shared__ float2 s_pb[D];            // {bh,bg}
  __shared__ __align__(16) float s_emb[NTYPES * ESTR];
  __shared__ float s_root[D];
  __shared__ float s_bias[O];
  __shared__ float s_psum[POOL ? (MAXB * 16) : 1];
  __shared__ float s_pcnt[POOL ? MAXB : 1];

  int tid = threadIdx.x;
  for (int k = tid; k < D; k += BS) {
    s_pa[k] = make_float4(wh[k], wh[D + k], wg[k], wg[D + k]);
    s_pb[k] = make_float2(bh[k], bg[k]);
    s_root[k] = root[k];
  }
  const float4* __restrict__ emb4 = (const float4*)emb;
  constexpr int T4 = NTYPES * D / 4;
  for (int k4 = tid; k4 < T4; k4 += BS) {
    float4 v = emb4[k4];
    int k = k4 * 4;
    int t = k / D, j = k - t * D;       // a float4 never crosses an emb row
    *(float4*)&s_emb[t * ESTR + j] = v;
  }
  if (tid < O) s_bias[tid] = bias[tid];
  if (POOL) {
    for (int i = tid; i < MAXB * 16; i += BS) s_psum[i] = 0.f;
    for (int i = tid; i < MAXB; i += BS) s_pcnt[i] = 0.f;
  }
  __syncthreads();

  int o = tid & 15;
  int sub = (tid >> 4) & 3;             // node-within-wave-tile (4 nodes/wave)
  int oc = (O == 16) ? o : ((o < O) ? o : 0);   // clamp idle lanes
  int gw = blockIdx.x * (BS / 64) + (tid >> 6); // global wave id
  int nw = gridDim.x * (BS / 64);               // total waves
  int nWT = (N + 3) >> 2;                       // 4-node tiles

  for (int wt = gw; wt < nWT; wt += nw) {
    int n = wt * 4 + sub;
    float acc = 0.f;
    int start = 0, end = 0;
    if (n < N) { start = row_ptr[n]; end = row_ptr[n + 1]; }
    for (int e = start; e < end; ++e) {
      int4 r = edges[e];
      int src = r.x, t = r.y;
      float f0 = __int_as_float(r.z), f1 = __int_as_float(r.w);
      const float* __restrict__ xr = xin + (size_t)src * IN_C;
      const float* __restrict__ er = s_emb + t * ESTR;
      #pragma unroll
      for (int i = 0; i < IN_C; ++i) {
        int k = i * O + oc;
        float4 a = s_pa[k];
        float2 b = s_pb[k];
        float h = fmaf(f0, a.x, fmaf(f1, a.y, b.x));
        float g = fmaf(f0, a.z, fmaf(f1, a.w, b.y));
        float w = fmaxf(fmaf(er[k], h, g), 0.f);
        acc = fmaf(xr[i], w, acc);
      }
    }

    if (n < N && o < O) {
      float inv = 1.0f / fmaxf((float)(end - start), 1.0f);
      float v = fmaf(acc, inv, s_bias[o]);
      const float* __restrict__ xr = xin + (size_t)n * IN_C;
      #pragma unroll
      for (int i = 0; i < IN_C; ++i) v = fmaf(xr[i], s_root[i * O + o], v);
      v = fmaxf(v, 0.f);
      if (!POOL) {
        hout[(size_t)n * O + o] = v;
      } else {
        if (ctype[n] == 1) {
          int b = bids[n];
          atomicAdd(&s_psum[b * 16 + o], v);
          if (o == 0) atomicAdd(&s_pcnt[b], 1.0f);
        }
      }
    }
  }

  if (POOL) {
    __syncthreads();
    for (int i = tid; i < B * 16; i += BS) {
      float v = s_psum[i];
      if (v != 0.f) atomicAdd(&hout[i], v);    // hout = psum (global)
    }
    for (int i = tid; i < B; i += BS) {
      float c = s_pcnt[i];
      if (c != 0.f) atomicAdd(&pcnt[i], c);
    }
  }
}

__global__ __launch_bounds__(256) void finalize_kernel(
    const float* __restrict__ psum, const float* __restrict__ pcnt,
    float* __restrict__ out, int B) {
  int i = blockIdx.x * blockDim.x + threadIdx.x;
  if (i >= B * OUT3) return;
  int b = i / OUT3;
  out[i] = psum[i] / fmaxf(pcnt[b], 1.0f);
}

// ---------------- launch ----------------
extern "C" void kernel_launch(void* const* d_in, const int* in_sizes, int n_in,
                              void* d_out, int out_size, void* d_ws, size_t ws_size,
                              hipStream_t stream)
{
  const float* x     = (const float*)d_in[0];
  const float* ef    = (const float*)d_in[1];
  const int*   et    = (const int*)d_in[2];
  const int*   esrc  = (const int*)d_in[3];
  const int*   edst  = (const int*)d_in[4];
  const int*   ctype = (const int*)d_in[5];
  const int*   bids  = (const int*)d_in[6];
  const float* emb1 = (const float*)d_in[8];
  const float* wh1  = (const float*)d_in[9];
  const float* bh1  = (const float*)d_in[10];
  const float* wg1  = (const float*)d_in[11];
  const float* bg1  = (const float*)d_in[12];
  const float* root1= (const float*)d_in[13];
  const float* bias1= (const float*)d_in[14];
  const float* emb2 = (const float*)d_in[15];
  const float* wh2  = (const float*)d_in[16];
  const float* bh2  = (const float*)d_in[17];
  const float* wg2  = (const float*)d_in[18];
  const float* bg2  = (const float*)d_in[19];
  const float* root2= (const float*)d_in[20];
  const float* bias2= (const float*)d_in[21];
  const float* emb3 = (const float*)d_in[22];
  const float* wh3  = (const float*)d_in[23];
  const float* bh3  = (const float*)d_in[24];
  const float* wg3  = (const float*)d_in[25];
  const float* bg3  = (const float*)d_in[26];
  const float* root3= (const float*)d_in[27];
  const float* bias3= (const float*)d_in[28];

  const int N = in_sizes[0] / IN1;
  const int E = in_sizes[2];
  const int B = out_size / OUT3;

  // workspace layout (16B-aligned sections)
  int4* edges   = (int4*)d_ws;                       // E recs (16B each)
  int*  deg     = (int*)(edges + E);                 // N
  int*  pos     = deg + N;                           // E
  int*  row_ptr = pos + E;                           // N+1
  int*  bsum    = row_ptr + (N + 1);                 // <=64 chunk sums
  float* h1     = (float*)(bsum + 64);               // N*HIDC
  float* h2     = h1 + (size_t)N * HIDC;             // N*HIDC
  float* psum   = h2 + (size_t)N * HIDC;             // B*16
  float* pcnt   = psum + (size_t)B * 16;             // B

  const int nChunk = (N + 1023) / 1024;              // 1024 deg entries per chunk

  zero2_kernel<<<128, 256, 0, stream>>>(deg, N, (int*)psum, B * 16 + B);
  hist_kernel<<<(E + 255) / 256, 256, 0, stream>>>(edst, deg, pos, E);
  scan_part_kernel<<<nChunk, 256, 0, stream>>>(deg, row_ptr, bsum, N);
  scan_bsum_kernel<<<1, 64, 0, stream>>>(bsum, row_ptr, nChunk, N);
  scan_add_kernel<<<(N + 255) / 256, 256, 0, stream>>>(row_ptr, bsum, N);
  permute_kernel<<<(E + 255) / 256, 256, 0, stream>>>(
      edst, esrc, et, (const float2*)ef, row_ptr, pos, edges, E);

  // persistent grids: all blocks co-resident (layers 1/2: 4 blocks/CU by LDS;
  // layer 3: 2 blocks/CU by wave limit at 1024 threads)
  const int gP = 1024;
  layer_kernel<IN1, HIDC, false, 256><<<gP, 256, 0, stream>>>(
      x, edges, row_ptr, emb1, wh1, bh1, wg1, bg1, root1, bias1,
      h1, nullptr, nullptr, nullptr, N, B);
  layer_kernel<HIDC, HIDC, false, 256><<<gP, 256, 0, stream>>>(
      h1, edges, row_ptr, emb2, wh2, bh2, wg2, bg2, root2, bias2,
      h2, nullptr, nullptr, nullptr, N, B);

  const int gQ = 512;
  layer_kernel<HIDC, OUT3, true, 1024><<<gQ, 1024, 0, stream>>>(
      h2, edges, row_ptr, emb3, wh3, bh3, wg3, bg3, root3, bias3,
      psum, ctype, bids, pcnt, N, B);

  finalize_kernel<<<1, 256, 0, stream>>>(psum, pcnt, (float*)d_out, B);
}